// Round 9
// baseline (171.110 us; speedup 1.0000x reference)
//
#include <hip/hip_runtime.h>
#include <stdint.h>

typedef short v8s  __attribute__((ext_vector_type(8)));
typedef float v16f __attribute__((ext_vector_type(16)));

#define KS    7
#define KPTS  9
#define OCH   128
#define CCH   128
#define NB    32
#define HW    56
#define PAD   3

#define HBLK  4
#define ROWS  10            // HBLK + 6
#define WP    72
#define CCK   32
#define NCC   4
#define HP    62
#define ROWB  (WP*CCK*2)        // 4608 B per padded x_t row (any layout)
#define XS_B  (ROWS*ROWB)       // 46080 B
#define AB_B  (4*OCH*CCK*2)     // 32768 B (ring of 4 A-slots, 8 KB each)
#define SMEM_B (XS_B + AB_B)    // 78848 B -> 2 blocks/CU

__device__ __forceinline__ unsigned short f2bf(float f) {
  unsigned int u = __builtin_bit_cast(unsigned int, f);
  u += 0x7fffu + ((u >> 16) & 1u);
  return (unsigned short)(u >> 16);
}

__device__ __forceinline__ void gl_lds16(const void* g, void* l) {
  __builtin_amdgcn_global_load_lds(
      (const __attribute__((address_space(1))) unsigned int*)g,
      (__attribute__((address_space(3))) unsigned int*)l, 16, 0, 0);
}

// Kernel construction: block = c (128), thread = o (128). Private 49-float row
// in LDS -> no atomics. kb = 32x32x16 A-fragment image (R5-validated):
// [cc][tap][f=kk*4+mt][lane64][8c] ; lane l holds o=mt*32+(l&31),
// k(within cc) = kk*16 + (l>>5)*8 + j  -> conv A-read is lane-linear 16B.
__global__ __launch_bounds__(128) void build_kern(
    const float* __restrict__ wgt, const float* __restrict__ P,
    unsigned short* __restrict__ kb) {
  __shared__ float sm[OCH*49];
  const int c = blockIdx.x, o = threadIdx.x;
  float* mine = &sm[o*49];
  #pragma unroll
  for (int j = 0; j < 49; ++j) mine[j] = 0.f;
  for (int k = 0; k < KPTS; ++k) {
    const float ph = fminf(fmaxf(P[c*KPTS + k], -3.f), 3.f) + 3.f;
    const float pw = fminf(fmaxf(P[CCH*KPTS + c*KPTS + k], -3.f), 3.f) + 3.f;
    const int ih = (int)floorf(ph), iw = (int)floorf(pw);
    const float rh = ph - (float)ih, rw = pw - (float)iw;
    const float wt = wgt[(o*CCH + c)*KPTS + k];
    mine[ih*KS + iw] += wt*(1.f-rh)*(1.f-rw);
    if (iw+1 < KS) mine[ih*KS + iw+1] += wt*(1.f-rh)*rw;
    if (ih+1 < KS) mine[(ih+1)*KS + iw] += wt*rh*(1.f-rw);
    if (ih+1 < KS && iw+1 < KS) mine[(ih+1)*KS + iw+1] += wt*rh*rw;
  }
  const int cc = c >> 5, c32 = c & 31;
  const int kk = c32 >> 4, g = (c32 >> 3) & 1, j = c & 7;
  const int mt = o >> 5, l5 = o & 31;
  const size_t base = ((size_t)cc*49*8 + kk*4 + mt)*512 + (g*32 + l5)*8 + j;
  for (int tap = 0; tap < 49; ++tap)
    kb[base + (size_t)tap*4096] = f2bf(mine[tap]);
}

// x [n][c][h][w] f32 -> x_t [n][cc][h'][kk2][g2][w'72][c8] bf16 (pads zero).
// A 32x32x16 B-frag read (col=lane&31, k=(lane>>5)*8+j) is then lane-linear
// 16B-stride in LDS at ANY kw shift -> conflict-free, no swizzle needed.
__global__ __launch_bounds__(256) void xpose(const float* __restrict__ x,
                                             unsigned short* __restrict__ xt) {
  __shared__ unsigned short lb[CCK][HW + 2];
  const int hp = blockIdx.x;
  const int cc = blockIdx.y;
  const int n  = blockIdx.z;
  const int t  = threadIdx.x;
  const int h  = hp - PAD;
  const bool valid = (unsigned)h < (unsigned)HW;
  if (valid) {
    const float* xb = x + ((size_t)(n*CCH + cc*CCK)*HW + h)*HW;
    #pragma unroll
    for (int k = 0; k < 7; ++k) {
      const int j = k*256 + t;
      const int c = j / HW, w = j % HW;
      lb[c][w] = f2bf(xb[(size_t)c*HW*HW + w]);
    }
  }
  __syncthreads();
  unsigned short* orow = xt + (size_t)((n*NCC + cc)*HP + hp)*(WP*4*8);
  for (int q = t; q < WP*4; q += 256) {   // q = (kk*2+g)*72 + w'
    const int kkg = q / WP, wq = q % WP;
    v8s v = (v8s){0,0,0,0,0,0,0,0};
    const int w = wq - PAD;
    if (valid && (unsigned)w < (unsigned)HW) {
      #pragma unroll
      for (int jj = 0; jj < 8; ++jj) v[jj] = (short)lb[kkg*8 + jj][w];
    }
    *(v8s*)&orow[q*8] = v;
  }
}

// Read tap T's 8 A-frags from ring slot T&3 (lane-linear).
#define PF_A(T, FA)                                                           \
  {                                                                           \
    const unsigned short* ap = ab + (size_t)((T) & 3)*4096;                   \
    _Pragma("unroll")                                                         \
    for (int f = 0; f < 8; ++f)                                               \
      FA[f] = *(const v8s*)&ap[f*512 + lane*8];                               \
  }

// Read tap T's 4 B-frags from xs (lane-linear 16B stride).
#define PF_B(T, FB)                                                           \
  {                                                                           \
    const int kh = (T)/7, kw = (T) - kh*7;                                    \
    const int r = wv + kh;                                                    \
    _Pragma("unroll")                                                         \
    for (int kk = 0; kk < 2; ++kk)                                            \
      _Pragma("unroll")                                                       \
      for (int nt = 0; nt < 2; ++nt)                                          \
        FB[kk*2 + nt] = *(const v8s*)&xs[((size_t)((r*2 + kk)*2 + g)*WP +     \
                                          nt*32 + kw + l5)*8];                \
  }

#define MFMA_T(FA, FB)                                                        \
  {                                                                           \
    __builtin_amdgcn_s_setprio(1);                                            \
    _Pragma("unroll")                                                         \
    for (int kk = 0; kk < 2; ++kk)                                            \
      _Pragma("unroll")                                                       \
      for (int mt = 0; mt < 4; ++mt)                                          \
        _Pragma("unroll")                                                     \
        for (int nt = 0; nt < 2; ++nt)                                        \
          acc[mt][nt] = __builtin_amdgcn_mfma_f32_32x32x16_bf16(              \
              FA[kk*4 + mt], FB[kk*2 + nt], acc[mt][nt], 0, 0, 0);            \
    __builtin_amdgcn_s_setprio(0);                                            \
  }

// Conv: grid 32 x 14 = 448, 4 waves (256 thr), wave = one h-row,
// per-wave tile M=128(o) x N=64(w), 32x32x16 MFMA, all LDS reads lane-linear.
// R4 schedule: reg-double-banked frags, 2-tap phases, ring of 4 A-slots.
__global__ __launch_bounds__(256, 2) void dcls_conv(
    const unsigned short* __restrict__ xt, const unsigned short* __restrict__ kb,
    const float* __restrict__ bias, float* __restrict__ out)
{
  extern __shared__ char smem[];
  unsigned short* xs = (unsigned short*)smem;            // [r10][kk2][g2][72][8]
  unsigned short* ab = (unsigned short*)(smem + XS_B);   // ring of 4 frag-images

  const int n   = blockIdx.x;
  const int hb  = blockIdx.y;
  const int tid = threadIdx.x;
  const int lane = tid & 63;
  const int wv   = tid >> 6;        // 0..3 = h-row within block
  const int l5   = lane & 31;
  const int g    = lane >> 5;

  v16f acc[4][2];
  {
    v16f z;
    #pragma unroll
    for (int i = 0; i < 16; ++i) z[i] = 0.f;
    #pragma unroll
    for (int m = 0; m < 4; ++m)
      #pragma unroll
      for (int t = 0; t < 2; ++t)
        acc[m][t] = z;
  }

  v8s fa0[8], fa1[8], fb0[4], fb1[4];

  for (int cc = 0; cc < NCC; ++cc) {
    // ---- stage xs: 45 linear KB-lines ----
    const char* src = (const char*)xt + (size_t)((n*NCC + cc)*HP + hb*HBLK)*ROWB;
    for (int i = wv; i < 45; i += 4)
      gl_lds16(src + i*1024 + lane*16, (char*)xs + i*1024);
    // ---- stage A(0), A(1) (8 KB frag-image tiles) ----
    const char* ks = (const char*)kb + (size_t)cc*49*8192;
    #pragma unroll
    for (int u = 0; u < 2; ++u)
      #pragma unroll
      for (int j = 0; j < 2; ++j)
        gl_lds16(ks + u*8192 + (wv*2 + j)*1024 + lane*16,
                 (char*)ab + u*8192 + (wv*2 + j)*1024);
    __syncthreads();

    PF_A(0, fa0)
    PF_B(0, fb0)

    #pragma unroll 1
    for (int p = 0; p < 24; ++p) {
      const int t0 = 2*p;
      // issue A(t0+2), A(t0+3) into the bank freed at last barrier
      {
        const int tp = t0 + 2;
        #pragma unroll
        for (int j = 0; j < 2; ++j)
          gl_lds16(ks + (size_t)tp*8192 + (wv*2 + j)*1024 + lane*16,
                   (char*)ab + (size_t)(tp & 3)*8192 + (wv*2 + j)*1024);
        const int tq = t0 + 3;
        if (tq < 49) {
          #pragma unroll
          for (int j = 0; j < 2; ++j)
            gl_lds16(ks + (size_t)tq*8192 + (wv*2 + j)*1024 + lane*16,
                     (char*)ab + (size_t)(tq & 3)*8192 + (wv*2 + j)*1024);
        }
      }
      // frags(t0+1) under MFMA(t0)
      PF_A(t0 + 1, fa1)
      PF_B(t0 + 1, fb1)
      MFMA_T(fa0, fb0)
      // B(t0+2) pre-barrier (xs static) under MFMA(t0+1)
      PF_B(t0 + 2, fb0)
      MFMA_T(fa1, fb1)
      __syncthreads();          // drains prefetch DMA; banks swap
      PF_A(t0 + 2, fa0)         // freshly-landed slot
    }
    MFMA_T(fa0, fb0)            // tap 48
    __syncthreads();            // protect xs/ring before next cc restage
  }

  // ---- epilogue: C/D 32x32: col=lane&31, row=(rr&3)+8*(rr>>2)+4*g ----
  const int h = hb*HBLK + wv;
  #pragma unroll
  for (int mt = 0; mt < 4; ++mt) {
    #pragma unroll
    for (int rr = 0; rr < 16; ++rr) {
      const int o = mt*32 + (rr & 3) + 8*(rr >> 2) + 4*g;
      const float bs = bias[o];
      out[((size_t)(n*OCH + o)*HW + h)*HW + l5] = acc[mt][0][rr] + bs;
      if (l5 < 24)
        out[((size_t)(n*OCH + o)*HW + h)*HW + 32 + l5] = acc[mt][1][rr] + bs;
    }
  }
}

extern "C" void kernel_launch(void* const* d_in, const int* in_sizes, int n_in,
                              void* d_out, int out_size, void* d_ws, size_t ws_size,
                              hipStream_t stream) {
  const float* x    = (const float*)d_in[0];
  const float* wgt  = (const float*)d_in[1];
  const float* P    = (const float*)d_in[2];
  const float* bias = (const float*)d_in[3];
  float* out = (float*)d_out;

  unsigned short* kb = (unsigned short*)d_ws;                       // 1.6 MB
  unsigned short* xt = (unsigned short*)((char*)d_ws + (2u<<20));   // 36.6 MB

  hipFuncSetAttribute((const void*)dcls_conv,
                      hipFuncAttributeMaxDynamicSharedMemorySize, SMEM_B);

  build_kern<<<CCH, OCH, 0, stream>>>(wgt, P, kb);
  xpose<<<dim3(HP, NCC, NB), 256, 0, stream>>>(x, xt);
  dcls_conv<<<dim3(NB, HW/HBLK), 256, SMEM_B, stream>>>(xt, kb, bias, out);
}